// Round 11
// baseline (618.660 us; speedup 1.0000x reference)
//
#include <hip/hip_runtime.h>
#include <hip/hip_bf16.h>

// StructuralEncoder: gather(3x128 f32) -> 384->256->256->128 MLP (relu,relu,linear)
// -> mean over 1M rows -> 128->256->128 head.
// R11: Layer-1 algebraic precompute. x@W1 = ent[t0]@W1a + rel[t1]@W1b + ent[t2]@W1c;
// precompute P_a/P_b/P_c (100K x 256 bf16 each, 51MB) per call, then main kernel
// does h1 = relu(Pa[t0]+Pb[t1]+Pc[t2]+b1) -- no L1 MFMA, no W1 stream, 3 barriers,
// 32KB LDS. Falls back to the R4 kernel (508us) if ws_size < 154MB.

#define EMBED 128
#define BM 64
#define NBUCKET 128
#define VOCAB 100000

typedef __bf16 bf16x8 __attribute__((ext_vector_type(8)));
typedef __bf16 bf16x4 __attribute__((ext_vector_type(4)));
typedef float f32x4 __attribute__((ext_vector_type(4)));

// pack W (K x N row-major) into 16(feature)x32(k) A-frag tiles for 16x16x32,
// and zero partial buckets.
__global__ void prep_all(const float* __restrict__ W1, const float* __restrict__ W2,
                         const float* __restrict__ W3,
                         __bf16* __restrict__ W1p, __bf16* __restrict__ W2p,
                         __bf16* __restrict__ W3p, float* __restrict__ prt) {
    int idx = blockIdx.x * 256 + threadIdx.x;
    if (idx < NBUCKET * 128) prt[idx] = 0.f;
    const float* src; __bf16* dst; int K, N, e;
    if (idx < 98304)       { src = W1; dst = W1p; K = 384; N = 256; e = idx; }
    else if (idx < 163840) { src = W2; dst = W2p; K = 256; N = 256; e = idx - 98304; }
    else if (idx < 196608) { src = W3; dst = W3p; K = 256; N = 128; e = idx - 163840; }
    else return;
    int j = e & 7, l = (e >> 3) & 63, t = e >> 9;
    int KT = K >> 5;
    int kt = t % KT, mt = t / KT;
    int k  = kt * 32 + (l >> 4) * 8 + j;
    int nc = mt * 16 + (l & 15);
    dst[e] = (__bf16)src[k * N + nc];
}

// ---- precompute P_a[v] = ent[v]@W1[0:128], P_b[v] = rel[v]@W1[128:256],
//      P_c[v] = ent[v]@W1[256:384]; 64 vocab rows per block ----
__global__ __launch_bounds__(256, 2) void precompute_P(
    const float* __restrict__ ent, const float* __restrict__ rel,
    const __bf16* __restrict__ W1p,
    __bf16* __restrict__ Pa, __bf16* __restrict__ Pb, __bf16* __restrict__ Pc)
{
    // xs: 64 rows x 512B = [ent row 256B | rel row 256B], 16B-chunk swizzle
    __shared__ unsigned char xs[32768];
    const int tid  = threadIdx.x;
    const int wave = tid >> 6;
    const int lane = tid & 63;
    const int l15  = lane & 15;
    const int l4   = lane >> 4;
    const int v0   = blockIdx.x * 64;
    const int sp   = tid >> 4;   // 0..15
    const int ch   = tid & 15;

#pragma unroll
    for (int p = 0; p < 4; p++) {
        int vr = p * 16 + sp;
        int v  = v0 + vr;
        int vc = v < VOCAB ? v : 0;
        const float* se = ent + (long)vc * EMBED + ch * 8;
        const float* sr = rel + (long)vc * EMBED + ch * 8;
        float4 e0 = *(const float4*)se, e1 = *(const float4*)(se + 4);
        float4 r0 = *(const float4*)sr, r1 = *(const float4*)(sr + 4);
        bf16x8 we, wr;
        we[0] = (__bf16)e0.x; we[1] = (__bf16)e0.y; we[2] = (__bf16)e0.z; we[3] = (__bf16)e0.w;
        we[4] = (__bf16)e1.x; we[5] = (__bf16)e1.y; we[6] = (__bf16)e1.z; we[7] = (__bf16)e1.w;
        wr[0] = (__bf16)r0.x; wr[1] = (__bf16)r0.y; wr[2] = (__bf16)r0.z; wr[3] = (__bf16)r0.w;
        wr[4] = (__bf16)r1.x; wr[5] = (__bf16)r1.y; wr[6] = (__bf16)r1.z; wr[7] = (__bf16)r1.w;
        int swz = (vr & 7) << 4;
        *(bf16x8*)(xs + ((vr * 512 + ch * 16) ^ swz))       = we;
        *(bf16x8*)(xs + ((vr * 512 + 256 + ch * 16) ^ swz)) = wr;
    }
    __syncthreads();

    __bf16* const outs[3] = {Pa, Pb, Pc};
#pragma unroll
    for (int ph = 0; ph < 3; ph++) {
        const int breg = (ph == 1) ? 256 : 0;   // Pb uses rel half, Pa/Pc use ent half
        f32x4 acc[4][4];
#pragma unroll
        for (int m = 0; m < 4; m++)
#pragma unroll
            for (int nn = 0; nn < 4; nn++) acc[m][nn] = (f32x4)(0.f);
#pragma unroll
        for (int kk = 0; kk < 4; kk++) {
            bf16x8 bfr[4];
#pragma unroll
            for (int nn = 0; nn < 4; nn++) {
                int s = nn * 16 + l15;
                int off = (s * 512 + breg + kk * 64 + l4 * 16) ^ ((s & 7) << 4);
                bfr[nn] = *(const bf16x8*)(xs + off);
            }
            bf16x8 afr[4];
#pragma unroll
            for (int m = 0; m < 4; m++)
                afr[m] = *(const bf16x8*)(W1p + ((wave * 4 + m) * 12 + ph * 4 + kk) * 512 + lane * 8);
#pragma unroll
            for (int m = 0; m < 4; m++)
#pragma unroll
                for (int nn = 0; nn < 4; nn++)
                    acc[m][nn] = __builtin_amdgcn_mfma_f32_16x16x32_bf16(
                        afr[m], bfr[nn], acc[m][nn], 0, 0, 0);
        }
        __bf16* out = outs[ph];
#pragma unroll
        for (int m = 0; m < 4; m++)
#pragma unroll
            for (int nn = 0; nn < 4; nn++) {
                int v = v0 + nn * 16 + l15;
                if (v < VOCAB) {
                    int f = wave * 64 + m * 16 + l4 * 4;
                    bf16x4 pk;
#pragma unroll
                    for (int j = 0; j < 4; j++) pk[j] = (__bf16)acc[m][nn][j];
                    *(bf16x4*)(out + (long)v * 256 + f) = pk;
                }
            }
    }
}

// ---- main fused MLP, P-table path: h1 built by gather+add, then L2/L3 MFMA ----
__global__ __launch_bounds__(256, 3) void mlp_mainP(
    const int* __restrict__ triples,
    const __bf16* __restrict__ Pa, const __bf16* __restrict__ Pb,
    const __bf16* __restrict__ Pc, const float* __restrict__ b1,
    const __bf16* __restrict__ W2p, const float* __restrict__ b2,
    const __bf16* __restrict__ W3p,
    float* __restrict__ part, int n)
{
    // LDS 32KB: h1s [0,32K) = 64 x 512B (swizzled); h2s overlays after B2
    __shared__ unsigned char lds[32768];
    unsigned char* h1s = lds;
    unsigned char* h2s = lds;

    const int tid  = threadIdx.x;
    const int wave = tid >> 6;
    const int lane = tid & 63;
    const int l15  = lane & 15;
    const int l4   = lane >> 4;
    const int s0   = blockIdx.x * BM;

    // ---- build h1 = relu(Pa[t0]+Pb[t1]+Pc[t2]+b1): 4 threads per sample ----
    {
        const int s = tid >> 2;      // sample 0..63
        const int q = tid & 3;       // 128B chunk (64 features)
        int g = s0 + s;
        const int* tp = triples + (long)(g < n ? g : 0) * 3;
        const uint4* ra = (const uint4*)(Pa + (long)tp[0] * 256 + q * 64);
        const uint4* rb = (const uint4*)(Pb + (long)tp[1] * 256 + q * 64);
        const uint4* rc = (const uint4*)(Pc + (long)tp[2] * 256 + q * 64);
        uint4 va[8], vb[8], vc[8];
#pragma unroll
        for (int i = 0; i < 8; i++) { va[i] = ra[i]; vb[i] = rb[i]; vc[i] = rc[i]; }
        const float* bp = b1 + q * 64;
        const int swz = (s & 7) << 4;
#pragma unroll
        for (int i = 0; i < 8; i++) {
            bf16x8 a = *reinterpret_cast<const bf16x8*>(&va[i]);
            bf16x8 b = *reinterpret_cast<const bf16x8*>(&vb[i]);
            bf16x8 c = *reinterpret_cast<const bf16x8*>(&vc[i]);
            f32x4 b0 = *(const f32x4*)(bp + i * 8);
            f32x4 b1v = *(const f32x4*)(bp + i * 8 + 4);
            bf16x8 r;
#pragma unroll
            for (int j = 0; j < 4; j++) {
                float v = (float)a[j] + (float)b[j] + (float)c[j] + b0[j];
                r[j] = (__bf16)(v > 0.f ? v : 0.f);
            }
#pragma unroll
            for (int j = 0; j < 4; j++) {
                float v = (float)a[4 + j] + (float)b[4 + j] + (float)c[4 + j] + b1v[j];
                r[4 + j] = (__bf16)(v > 0.f ? v : 0.f);
            }
            int off = (s * 512 + q * 128 + i * 16) ^ swz;
            *(bf16x8*)(h1s + off) = r;
        }
    }
    __syncthreads();  // B1: h1 ready

    // ========== Layer 2: h2 = relu(h1 @ W2 + b2), K=256 ==========
    f32x4 acc2[2][4];
    f32x4 acc2b[2][4];
    {
        const int fb = wave * 64;
#pragma unroll
        for (int m = 0; m < 2; m++) {
            f32x4 bias = *(const f32x4*)(b2 + fb + m * 16 + l4 * 4);
            f32x4 biasb = *(const f32x4*)(b2 + fb + (m + 2) * 16 + l4 * 4);
#pragma unroll
            for (int nn = 0; nn < 4; nn++) { acc2[m][nn] = bias; acc2b[m][nn] = biasb; }
        }
    }
    __builtin_amdgcn_s_setprio(1);
#pragma unroll
    for (int kk = 0; kk < 8; kk++) {
        bf16x8 bfr[4];
#pragma unroll
        for (int nn = 0; nn < 4; nn++) {
            int s = nn * 16 + l15;
            int off = (s * 512 + kk * 64 + l4 * 16) ^ ((s & 7) << 4);
            bfr[nn] = *(const bf16x8*)(h1s + off);
        }
        bf16x8 afr[4];
#pragma unroll
        for (int m = 0; m < 4; m++)
            afr[m] = *(const bf16x8*)(W2p + ((wave * 4 + m) * 8 + kk) * 512 + lane * 8);
#pragma unroll
        for (int m = 0; m < 2; m++)
#pragma unroll
            for (int nn = 0; nn < 4; nn++) {
                acc2[m][nn] = __builtin_amdgcn_mfma_f32_16x16x32_bf16(
                    afr[m], bfr[nn], acc2[m][nn], 0, 0, 0);
                acc2b[m][nn] = __builtin_amdgcn_mfma_f32_16x16x32_bf16(
                    afr[m + 2], bfr[nn], acc2b[m][nn], 0, 0, 0);
            }
    }
    __builtin_amdgcn_s_setprio(0);
    __syncthreads();  // B2: all h1 reads done; h2 may overlay
    // write h2 (relu, bf16)
#pragma unroll
    for (int m = 0; m < 4; m++) {
        int f0 = wave * 64 + m * 16 + l4 * 4;
#pragma unroll
        for (int nn = 0; nn < 4; nn++) {
            int s = nn * 16 + l15;
            bf16x4 p;
#pragma unroll
            for (int j = 0; j < 4; j++) {
                float v = (m < 2) ? acc2[m][nn][j] : acc2b[m - 2][nn][j];
                p[j] = (__bf16)(v > 0.f ? v : 0.f);
            }
            int off = (s * 512 + f0 * 2) ^ ((s & 7) << 4);
            *(bf16x4*)(h2s + off) = p;
        }
    }
    __syncthreads();  // B3: h2 ready

    // ========== Layer 3: enc = h2 @ W3 (bias in head), K=256 ==========
    f32x4 acc3[2][4];
#pragma unroll
    for (int m = 0; m < 2; m++)
#pragma unroll
        for (int nn = 0; nn < 4; nn++)
            acc3[m][nn] = (f32x4)(0.f);
    __builtin_amdgcn_s_setprio(1);
#pragma unroll
    for (int kk = 0; kk < 8; kk++) {
        bf16x8 bfr[4];
#pragma unroll
        for (int nn = 0; nn < 4; nn++) {
            int s = nn * 16 + l15;
            int off = (s * 512 + kk * 64 + l4 * 16) ^ ((s & 7) << 4);
            bfr[nn] = *(const bf16x8*)(h2s + off);
        }
        bf16x8 afr[2];
#pragma unroll
        for (int m = 0; m < 2; m++)
            afr[m] = *(const bf16x8*)(W3p + ((wave * 2 + m) * 8 + kk) * 512 + lane * 8);
#pragma unroll
        for (int m = 0; m < 2; m++)
#pragma unroll
            for (int nn = 0; nn < 4; nn++)
                acc3[m][nn] = __builtin_amdgcn_mfma_f32_16x16x32_bf16(
                    afr[m], bfr[nn], acc3[m][nn], 0, 0, 0);
    }
    __builtin_amdgcn_s_setprio(0);
    // reduce over samples, accumulate into bucket
    {
        float* bucket = part + (blockIdx.x & (NBUCKET - 1)) * 128;
#pragma unroll
        for (int m = 0; m < 2; m++) {
#pragma unroll
            for (int j = 0; j < 4; j++) {
                float v = 0.f;
#pragma unroll
                for (int nn = 0; nn < 4; nn++) {
                    int g = s0 + nn * 16 + l15;
                    float t = acc3[m][nn][j];
                    v += (g < n) ? t : 0.f;
                }
                for (int off = 1; off < 16; off <<= 1) v += __shfl_xor(v, off);
                if (l15 == 0) {
                    int f = wave * 32 + m * 16 + l4 * 4 + j;
                    atomicAdd(bucket + f, v);
                }
            }
        }
    }
}

// ---- fallback: R4 kernel verbatim (508us) ----
__global__ __launch_bounds__(256, 3) void mlp_main_r4(
    const int* __restrict__ triples,
    const float* __restrict__ ent, const float* __restrict__ rel,
    const __bf16* __restrict__ W1p, const float* __restrict__ b1,
    const __bf16* __restrict__ W2p, const float* __restrict__ b2,
    const __bf16* __restrict__ W3p,
    float* __restrict__ part, int n)
{
    __shared__ unsigned char lds[49152];
    unsigned char* xs  = lds;
    unsigned char* h1s = lds;
    unsigned char* h2s = lds;
    const int tid  = threadIdx.x;
    const int wave = tid >> 6;
    const int lane = tid & 63;
    const int l15  = lane & 15;
    const int l4   = lane >> 4;
    const int s0   = blockIdx.x * BM;
    const int sp   = tid >> 4;
    const int ch   = tid & 15;

    int rows[3][4];
#pragma unroll
    for (int p = 0; p < 4; p++) {
        int g = s0 + p * 16 + sp;
        const int* t = triples + (g < n ? g : 0) * 3;
        rows[0][p] = t[0]; rows[1][p] = t[1]; rows[2][p] = t[2];
    }
    float4 ga[3][4], gb[3][4];
#pragma unroll
    for (int c = 0; c < 3; c++) {
        const float* tbl = (c == 1) ? rel : ent;
#pragma unroll
        for (int p = 0; p < 4; p++) {
            const float* src = tbl + (long)rows[c][p] * EMBED + ch * 8;
            ga[c][p] = *(const float4*)src;
            gb[c][p] = *(const float4*)(src + 4);
        }
    }
#pragma unroll
    for (int c = 0; c < 3; c++)
#pragma unroll
        for (int p = 0; p < 4; p++) {
            bf16x8 w;
            w[0] = (__bf16)ga[c][p].x; w[1] = (__bf16)ga[c][p].y;
            w[2] = (__bf16)ga[c][p].z; w[3] = (__bf16)ga[c][p].w;
            w[4] = (__bf16)gb[c][p].x; w[5] = (__bf16)gb[c][p].y;
            w[6] = (__bf16)gb[c][p].z; w[7] = (__bf16)gb[c][p].w;
            int s = p * 16 + sp;
            int off = (s * 768 + c * 256 + ch * 16) ^ ((s & 7) << 4);
            *(bf16x8*)(xs + off) = w;
        }
    __syncthreads();

    f32x4 acc[4][4];
    {
        const int fb = wave * 64;
#pragma unroll
        for (int m = 0; m < 4; m++) {
            f32x4 bias = *(const f32x4*)(b1 + fb + m * 16 + l4 * 4);
#pragma unroll
            for (int nn = 0; nn < 4; nn++) acc[m][nn] = bias;
        }
    }
    __builtin_amdgcn_s_setprio(1);
#pragma unroll
    for (int kk = 0; kk < 12; kk++) {
        bf16x8 bfr[4];
#pragma unroll
        for (int nn = 0; nn < 4; nn++) {
            int s = nn * 16 + l15;
            int off = (s * 768 + kk * 64 + l4 * 16) ^ ((s & 7) << 4);
            bfr[nn] = *(const bf16x8*)(xs + off);
        }
        bf16x8 afr[4];
#pragma unroll
        for (int m = 0; m < 4; m++)
            afr[m] = *(const bf16x8*)(W1p + ((wave * 4 + m) * 12 + kk) * 512 + lane * 8);
#pragma unroll
        for (int m = 0; m < 4; m++)
#pragma unroll
            for (int nn = 0; nn < 4; nn++)
                acc[m][nn] = __builtin_amdgcn_mfma_f32_16x16x32_bf16(
                    afr[m], bfr[nn], acc[m][nn], 0, 0, 0);
    }
    __builtin_amdgcn_s_setprio(0);
    __syncthreads();
#pragma unroll
    for (int m = 0; m < 4; m++) {
        int f0 = wave * 64 + m * 16 + l4 * 4;
#pragma unroll
        for (int nn = 0; nn < 4; nn++) {
            int s = nn * 16 + l15;
            bf16x4 p;
#pragma unroll
            for (int j = 0; j < 4; j++) {
                float v = acc[m][nn][j];
                p[j] = (__bf16)(v > 0.f ? v : 0.f);
            }
            int off = (s * 512 + f0 * 2) ^ ((s & 7) << 4);
            *(bf16x4*)(h1s + off) = p;
        }
    }
    __syncthreads();

    f32x4 acc2[4][4];
    {
        const int fb = wave * 64;
#pragma unroll
        for (int m = 0; m < 4; m++) {
            f32x4 bias = *(const f32x4*)(b2 + fb + m * 16 + l4 * 4);
#pragma unroll
            for (int nn = 0; nn < 4; nn++) acc2[m][nn] = bias;
        }
    }
    __builtin_amdgcn_s_setprio(1);
#pragma unroll
    for (int kk = 0; kk < 8; kk++) {
        bf16x8 bfr[4];
#pragma unroll
        for (int nn = 0; nn < 4; nn++) {
            int s = nn * 16 + l15;
            int off = (s * 512 + kk * 64 + l4 * 16) ^ ((s & 7) << 4);
            bfr[nn] = *(const bf16x8*)(h1s + off);
        }
        bf16x8 afr[4];
#pragma unroll
        for (int m = 0; m < 4; m++)
            afr[m] = *(const bf16x8*)(W2p + ((wave * 4 + m) * 8 + kk) * 512 + lane * 8);
#pragma unroll
        for (int m = 0; m < 4; m++)
#pragma unroll
            for (int nn = 0; nn < 4; nn++)
                acc2[m][nn] = __builtin_amdgcn_mfma_f32_16x16x32_bf16(
                    afr[m], bfr[nn], acc2[m][nn], 0, 0, 0);
    }
    __builtin_amdgcn_s_setprio(0);
    __syncthreads();
#pragma unroll
    for (int m = 0; m < 4; m++) {
        int f0 = wave * 64 + m * 16 + l4 * 4;
#pragma unroll
        for (int nn = 0; nn < 4; nn++) {
            int s = nn * 16 + l15;
            bf16x4 p;
#pragma unroll
            for (int j = 0; j < 4; j++) {
                float v = acc2[m][nn][j];
                p[j] = (__bf16)(v > 0.f ? v : 0.f);
            }
            int off = (s * 512 + f0 * 2) ^ ((s & 7) << 4);
            *(bf16x4*)(h2s + off) = p;
        }
    }
    __syncthreads();

    f32x4 acc3[2][4];
#pragma unroll
    for (int m = 0; m < 2; m++)
#pragma unroll
        for (int nn = 0; nn < 4; nn++)
            acc3[m][nn] = (f32x4)(0.f);
    __builtin_amdgcn_s_setprio(1);
#pragma unroll
    for (int kk = 0; kk < 8; kk++) {
        bf16x8 bfr[4];
#pragma unroll
        for (int nn = 0; nn < 4; nn++) {
            int s = nn * 16 + l15;
            int off = (s * 512 + kk * 64 + l4 * 16) ^ ((s & 7) << 4);
            bfr[nn] = *(const bf16x8*)(h2s + off);
        }
        bf16x8 afr[2];
#pragma unroll
        for (int m = 0; m < 2; m++)
            afr[m] = *(const bf16x8*)(W3p + ((wave * 2 + m) * 8 + kk) * 512 + lane * 8);
#pragma unroll
        for (int m = 0; m < 2; m++)
#pragma unroll
            for (int nn = 0; nn < 4; nn++)
                acc3[m][nn] = __builtin_amdgcn_mfma_f32_16x16x32_bf16(
                    afr[m], bfr[nn], acc3[m][nn], 0, 0, 0);
    }
    __builtin_amdgcn_s_setprio(0);
    {
        float* bucket = part + (blockIdx.x & (NBUCKET - 1)) * 128;
#pragma unroll
        for (int m = 0; m < 2; m++) {
#pragma unroll
            for (int j = 0; j < 4; j++) {
                float v = 0.f;
#pragma unroll
                for (int nn = 0; nn < 4; nn++) {
                    int g = s0 + nn * 16 + l15;
                    float t = acc3[m][nn][j];
                    v += (g < n) ? t : 0.f;
                }
                for (int off = 1; off < 16; off <<= 1) v += __shfl_xor(v, off);
                if (l15 == 0) {
                    int f = wave * 32 + m * 16 + l4 * 4 + j;
                    atomicAdd(bucket + f, v);
                }
            }
        }
    }
}

// ---- head: agg = sum/n + b3; out = relu(agg@Wf1+bf1)@Wf2+bf2 (f32) ----
__global__ void head_kernel(const float* __restrict__ part, const float* __restrict__ b3,
                            const float* __restrict__ Wf1, const float* __restrict__ bf1,
                            const float* __restrict__ Wf2, const float* __restrict__ bf2,
                            float* __restrict__ out, int n)
{
    __shared__ float agg[128];
    __shared__ float t[256];
    const int tid = threadIdx.x;
    if (tid < 128) {
        float s = 0.f;
        for (int b = 0; b < NBUCKET; b++) s += part[b * 128 + tid];
        agg[tid] = s / (float)n + b3[tid];
    }
    __syncthreads();
    {
        float a = bf1[tid];
        for (int k = 0; k < 128; k++) a += agg[k] * Wf1[k * 256 + tid];
        t[tid] = a > 0.f ? a : 0.f;
    }
    __syncthreads();
    if (tid < 128) {
        float o = bf2[tid];
        for (int i = 0; i < 256; i++) o += t[i] * Wf2[i * 128 + tid];
        out[tid] = o;
    }
}

extern "C" void kernel_launch(void* const* d_in, const int* in_sizes, int n_in,
                              void* d_out, int out_size, void* d_ws, size_t ws_size,
                              hipStream_t stream) {
    const int*   triples = (const int*)d_in[0];
    const float* ent     = (const float*)d_in[1];
    const float* rel     = (const float*)d_in[2];
    const float* W1      = (const float*)d_in[3];
    const float* b1      = (const float*)d_in[4];
    const float* W2      = (const float*)d_in[5];
    const float* b2      = (const float*)d_in[6];
    const float* W3      = (const float*)d_in[7];
    const float* b3      = (const float*)d_in[8];
    const float* Wf1     = (const float*)d_in[9];
    const float* bf1     = (const float*)d_in[10];
    const float* Wf2     = (const float*)d_in[11];
    const float* bf2     = (const float*)d_in[12];
    float* out = (float*)d_out;
    const int n = in_sizes[0] / 3;

    // ws layout (bytes): W1p[0,196608) W2p[196608,327680) W3p[327680,393216)
    //                    part[393216,458752) Pa/Pb/Pc[458752, +3*51.2MB)
    __bf16* W1p = (__bf16*)d_ws;
    __bf16* W2p = (__bf16*)((char*)d_ws + 196608);
    __bf16* W3p = (__bf16*)((char*)d_ws + 327680);
    float*  prt = (float*)((char*)d_ws + 393216);
    const size_t P_OFF = 458752;
    const size_t P_ELEMS = (size_t)VOCAB * 256;           // per table
    const size_t NEED = P_OFF + 3 * P_ELEMS * sizeof(__bf16);

    prep_all<<<768, 256, 0, stream>>>(W1, W2, W3, W1p, W2p, W3p, prt);

    const int blocks = (n + BM - 1) / BM;
    if (ws_size >= NEED) {
        __bf16* Pa = (__bf16*)((char*)d_ws + P_OFF);
        __bf16* Pb = Pa + P_ELEMS;
        __bf16* Pc = Pb + P_ELEMS;
        precompute_P<<<(VOCAB + 63) / 64, 256, 0, stream>>>(ent, rel, W1p, Pa, Pb, Pc);
        mlp_mainP<<<blocks, 256, 0, stream>>>(triples, Pa, Pb, Pc, b1, W2p, b2, W3p, prt, n);
    } else {
        mlp_main_r4<<<blocks, 256, 0, stream>>>(triples, ent, rel, W1p, b1, W2p, b2, W3p, prt, n);
    }
    head_kernel<<<1, 256, 0, stream>>>(prt, b3, Wf1, bf1, Wf2, bf2, out, n);
}